// Round 4
// baseline (164.766 us; speedup 1.0000x reference)
//
#include <hip/hip_runtime.h>
#include <math.h>

// Sobel 3D magnitude, separable: S=[1,2,1], D=[1,0,-1]
// gx = Sz(Sy(Dx)), gy = Sz(Dy(Sx)), gz = Dz(Sy(Sx)); out = sqrt(gx^2+gy^2+gz^2+1e-6)
// x: (2,32,64,128,128) fp32.
// R4: grid == residency (8 blocks/CU x 256 CUs = 2048 = grid), prefetch depth 2,
// row-accumulated xy pass to cap register pressure under the 64-VGPR budget.

typedef float floatx4 __attribute__((ext_vector_type(4)));

constexpr int W   = 128;
constexpr int H   = 128;
constexpr int DZ  = 64;
constexpr int NC  = 2 * 32;
constexpr int TH  = 8;            // output rows per block
constexpr int HBLKS = H / TH;     // 16
constexpr int ZCH = 2;            // z chunks
constexpr int ZLEN = DZ / ZCH;    // 32
constexpr int LROWS = TH + 2;     // 10 staged rows (y-halo)

__global__ __launch_bounds__(256, 8)
void sobel3d_kernel(const float* __restrict__ xg, float* __restrict__ og) {
    const int tid = threadIdx.x;
    const int tx  = tid & 31;      // w segment: pixels 4*tx..4*tx+3
    const int ty  = tid >> 5;      // row 0..7
    int b = blockIdx.x;
    const int hblk = b % HBLKS; b /= HBLKS;
    const int zc   = b % ZCH;   b /= ZCH;
    const int nc   = b;
    const int h0   = hblk * TH;
    const int za   = zc * ZLEN;
    const int zb   = za + ZLEN;    // exclusive; plane zb is the last needed

    const float* __restrict__ xp = xg + (size_t)nc * DZ * H * W;
    float* __restrict__ op       = og + (size_t)nc * DZ * H * W;

    __shared__ float lds[2][LROWS][W];

    // staging: all 256 threads -> rows 0..7; tid<64 additionally -> rows 8..9
    const int  r0   = ty;
    const int  h_a  = h0 - 1 + r0;
    const bool has1 = (tid < 64);
    const int  r1   = 8 + ty;
    const int  h_b  = h0 - 1 + r1;

    auto gload = [&](int z, int h) -> floatx4 {
        if ((unsigned)z < (unsigned)DZ && (unsigned)h < (unsigned)H)
            return *(const floatx4*)(xp + ((size_t)z * H + h) * W + 4 * tx);
        return (floatx4){0.f, 0.f, 0.f, 0.f};
    };
    auto lwrite = [&](int buf, floatx4 v0, floatx4 v1) {
        *(floatx4*)&lds[buf][r0][4 * tx] = v0;
        if (has1) *(floatx4*)&lds[buf][r1][4 * tx] = v1;
    };

    // horizontal pass for one LDS row: Sx, Dx of this thread's 4 pixels
    auto row_sd = [&](int buf, int row, floatx4& s, floatx4& d) {
        floatx4 q = *(const floatx4*)&lds[buf][row][4 * tx];
        float xm1 = __shfl_up(q.w, 1, 64);
        if (tx == 0)  xm1 = 0.f;
        float xp4 = __shfl_down(q.x, 1, 64);
        if (tx == 31) xp4 = 0.f;
        s.x = xm1 + 2.f * q.x + q.y;
        s.y = q.x + 2.f * q.y + q.z;
        s.z = q.y + 2.f * q.z + q.w;
        s.w = q.z + 2.f * q.w + xp4;
        d.x = xm1 - q.y;
        d.y = q.x - q.z;
        d.z = q.y - q.w;
        d.w = q.z - xp4;
    };

    // full xy pass, row-accumulated (low live-register count):
    // cc=Sy(Sx), dd=Dy(Sx), ee=Sy(Dx)
    auto compute_plane = [&](int buf, floatx4& cc, floatx4& dd, floatx4& ee) {
        floatx4 s, d;
        row_sd(buf, ty, s, d);
        cc = s; dd = s; ee = d;
        row_sd(buf, ty + 1, s, d);
        cc += 2.f * s; ee += 2.f * d;
        row_sd(buf, ty + 2, s, d);
        cc += s; dd -= s; ee += d;
    };

    // rolling 2-plane state: prev (z-1) and curr (z)
    floatx4 cP, dP, eP, cC, dCv, eC;

    // ---- prologue ----
    {
        floatx4 a0 = gload(za - 1, h_a), a1 = gload(za - 1, h_b);
        floatx4 b0 = gload(za,     h_a), b1 = gload(za,     h_b);
        lwrite(0, a0, a1);
        lwrite(1, b0, b1);
    }
    __syncthreads();
    compute_plane(0, cP, dP, eP);   // plane za-1
    compute_plane(1, cC, dCv, eC);  // plane za
    floatx4 rA0, rA1;               // in-flight plane (to be written next)
    {
        floatx4 p0 = gload(za + 1, h_a), p1 = gload(za + 1, h_b);
        rA0 = gload(za + 2, h_a); rA1 = gload(za + 2, h_b);
        __syncthreads();            // all waves done reading buf0
        lwrite(0, p0, p1);
    }
    __syncthreads();
    int cur = 0;  // invariant at loop top: buf[cur]=plane z+1, (rA0,rA1)=plane z+2

    size_t obase = ((size_t)za * H + (h0 + ty)) * W + 4 * tx;
    const size_t ostep = (size_t)H * W;

    for (int z = za; z < zb; ++z) {
        // issue plane z+3 load (not needed beyond zb -> zeros, no fetch)
        int zn = z + 3;
        if (zn > zb) zn = -1;
        floatx4 n0 = gload(zn, h_a), n1 = gload(zn, h_b);

        // compute plane z+1 from buf[cur] (overlaps outstanding loads)
        floatx4 c2, d2, e2;
        compute_plane(cur, c2, d2, e2);

        // stage plane z+2 from regs loaded one iteration ago
        lwrite(cur ^ 1, rA0, rA1);

        // emit output plane z
        floatx4 gx = eP + 2.f * eC + e2;
        floatx4 gy = dP + 2.f * dCv + d2;
        floatx4 gz = cP - c2;
        floatx4 o;
        o.x = __builtin_amdgcn_sqrtf(gx.x * gx.x + gy.x * gy.x + gz.x * gz.x + 1e-6f);
        o.y = __builtin_amdgcn_sqrtf(gx.y * gx.y + gy.y * gy.y + gz.y * gz.y + 1e-6f);
        o.z = __builtin_amdgcn_sqrtf(gx.z * gx.z + gy.z * gy.z + gz.z * gz.z + 1e-6f);
        o.w = __builtin_amdgcn_sqrtf(gx.w * gx.w + gy.w * gy.w + gz.w * gz.w + 1e-6f);
        __builtin_nontemporal_store(o, (floatx4*)(op + obase));

        // shift rolling window; promote in-flight regs
        cP = cC; cC = c2;
        dP = dCv; dCv = d2;
        eP = eC; eC = e2;
        rA0 = n0; rA1 = n1;
        obase += ostep;

        __syncthreads();
        cur ^= 1;
    }
}

extern "C" void kernel_launch(void* const* d_in, const int* in_sizes, int n_in,
                              void* d_out, int out_size, void* d_ws, size_t ws_size,
                              hipStream_t stream) {
    const float* x = (const float*)d_in[0];
    float* out = (float*)d_out;
    dim3 grid(NC * ZCH * HBLKS);   // 64*2*16 = 2048 blocks == 8/CU residency
    dim3 block(256);
    sobel3d_kernel<<<grid, block, 0, stream>>>(x, out);
}

// Round 5
// 99.657 us; speedup vs baseline: 1.6533x; 1.6533x over previous
//
#include <hip/hip_runtime.h>

// Sobel 3D magnitude, separable: S=[1,2,1], D=[1,0,-1]
// gx = Sz(Sy(Dx)), gy = Sz(Dy(Sx)), gz = Dz(Sy(Sx)); out = sqrt(gx^2+gy^2+gz^2+1e-6)
// x: (2,32,64,128,128) fp32.
// R5: NO LDS, NO BARRIERS. Each thread reads rows h-1,h,h+1 directly from
// global (L1/L2 absorb the 3x overlap between adjacent-ty threads), keeps a
// 2-plane rolling window of xy-intermediates in registers, and prefetches the
// next z-plane's rows one full iteration ahead. Waves run fully independent,
// so no vmcnt(0)+barrier drain ever serializes the pipeline.

typedef float floatx4 __attribute__((ext_vector_type(4)));

constexpr int W   = 128;
constexpr int H   = 128;
constexpr int DZ  = 64;
constexpr int NC  = 2 * 32;
constexpr int TH  = 8;            // output rows per block
constexpr int HBLKS = H / TH;     // 16
constexpr int ZCH = 2;            // z chunks
constexpr int ZLEN = DZ / ZCH;    // 32

__global__ __launch_bounds__(256, 6)
void sobel3d_kernel(const float* __restrict__ xg, float* __restrict__ og) {
    const int tid = threadIdx.x;
    const int tx  = tid & 31;      // w segment: pixels 4*tx..4*tx+3
    const int ty  = tid >> 5;      // row 0..7 within tile
    int b = blockIdx.x;
    const int hblk = b % HBLKS; b /= HBLKS;
    const int zc   = b % ZCH;   b /= ZCH;
    const int nc   = b;
    const int h    = hblk * TH + ty;   // this thread's output row
    const int za   = zc * ZLEN;
    const int zb   = za + ZLEN;        // exclusive

    const float* __restrict__ xp = xg + (size_t)nc * DZ * H * W;
    float* __restrict__ op       = og + (size_t)nc * DZ * H * W;

    const bool hm = (h > 0);
    const bool hp = (h < H - 1);
    const size_t roff = (size_t)h * W + 4 * tx;

    // load the 3 rows (h-1, h, h+1) of plane z for this thread's 4 pixels
    auto gload3 = [&](int z, floatx4& a, floatx4& bq, floatx4& c) {
        if ((unsigned)z < (unsigned)DZ) {
            const float* p = xp + (size_t)z * H * W + roff;
            a  = hm ? *(const floatx4*)(p - W) : (floatx4){0.f, 0.f, 0.f, 0.f};
            bq = *(const floatx4*)p;
            c  = hp ? *(const floatx4*)(p + W) : (floatx4){0.f, 0.f, 0.f, 0.f};
        } else {
            a = bq = c = (floatx4){0.f, 0.f, 0.f, 0.f};
        }
    };

    // horizontal pass on one row: Sx, Dx (w-halo via intra-wave shuffles;
    // lanes at tx==0/31 are tile edges -> zero pad, also masks cross-row pulls)
    auto row_sd = [&](floatx4 q, floatx4& s, floatx4& d) {
        float xm1 = __shfl_up(q.w, 1, 64);
        if (tx == 0)  xm1 = 0.f;
        float xp4 = __shfl_down(q.x, 1, 64);
        if (tx == 31) xp4 = 0.f;
        s.x = xm1 + 2.f * q.x + q.y;
        s.y = q.x + 2.f * q.y + q.z;
        s.z = q.y + 2.f * q.z + q.w;
        s.w = q.z + 2.f * q.w + xp4;
        d.x = xm1 - q.y;
        d.y = q.x - q.z;
        d.z = q.y - q.w;
        d.w = q.z - xp4;
    };

    // full xy pass from 3 raw rows: cc=Sy(Sx), dd=Dy(Sx), ee=Sy(Dx)
    auto plane_sde = [&](floatx4 qA, floatx4 qB, floatx4 qC,
                         floatx4& cc, floatx4& dd, floatx4& ee) {
        floatx4 s, d;
        row_sd(qA, s, d); cc = s;       dd = s;  ee = d;
        row_sd(qB, s, d); cc += 2.f * s;         ee += 2.f * d;
        row_sd(qC, s, d); cc += s;      dd -= s; ee += d;
    };

    // rolling 2-plane intermediates: P = plane z-1, C = plane z
    floatx4 cP, dP, eP, cC, dCv, eC;
    {
        floatx4 a, bq, c;
        gload3(za - 1, a, bq, c); plane_sde(a, bq, c, cP, dP, eP);
        gload3(za,     a, bq, c); plane_sde(a, bq, c, cC, dCv, eC);
    }
    // prefetched raw rows of plane z+1 (consumed next iteration top)
    floatx4 pA, pB, pC;
    gload3(za + 1, pA, pB, pC);

    size_t obase = (size_t)za * H * W + roff;
    const size_t ostep = (size_t)H * W;

    for (int z = za; z < zb; ++z) {
        // issue plane z+2 rows now; consumed next iteration (latency hidden)
        int zn = z + 2;
        if (zn > zb) zn = DZ;          // invalid -> zeros, no fetch
        floatx4 nA, nB, nC;
        gload3(zn, nA, nB, nC);

        // compute plane z+1 intermediates from rows prefetched last iteration
        floatx4 c2, d2, e2;
        plane_sde(pA, pB, pC, c2, d2, e2);

        // emit output plane z
        floatx4 gx = eP + 2.f * eC + e2;
        floatx4 gy = dP + 2.f * dCv + d2;
        floatx4 gz = cP - c2;
        floatx4 o;
        o.x = __builtin_amdgcn_sqrtf(gx.x * gx.x + gy.x * gy.x + gz.x * gz.x + 1e-6f);
        o.y = __builtin_amdgcn_sqrtf(gx.y * gx.y + gy.y * gy.y + gz.y * gz.y + 1e-6f);
        o.z = __builtin_amdgcn_sqrtf(gx.z * gx.z + gy.z * gy.z + gz.z * gz.z + 1e-6f);
        o.w = __builtin_amdgcn_sqrtf(gx.w * gx.w + gy.w * gy.w + gz.w * gz.w + 1e-6f);
        __builtin_nontemporal_store(o, (floatx4*)(op + obase));

        // roll windows
        cP = cC;  cC  = c2;
        dP = dCv; dCv = d2;
        eP = eC;  eC  = e2;
        pA = nA;  pB  = nB;  pC = nC;
        obase += ostep;
    }
}

extern "C" void kernel_launch(void* const* d_in, const int* in_sizes, int n_in,
                              void* d_out, int out_size, void* d_ws, size_t ws_size,
                              hipStream_t stream) {
    const float* x = (const float*)d_in[0];
    float* out = (float*)d_out;
    dim3 grid(NC * ZCH * HBLKS);   // 64*2*16 = 2048 blocks
    dim3 block(256);
    sobel3d_kernel<<<grid, block, 0, stream>>>(x, out);
}